// Round 6
// baseline (510.936 us; speedup 1.0000x reference)
//
#include <hip/hip_runtime.h>
#include <math.h>

#define NWAVE 64
#define DMODEL 128
#define BLOCK 256
#define N_FIXED 768
#define TILE 32
#define T_TILES (N_FIXED / TILE)              // 24
#define TPAIRS (T_TILES * (T_TILES + 1) / 2)  // 300

// Symmetric pair-tile kernel: r_ij = r_ji, and the (i<-j) / (j<-i)
// contributions are identical (both gated by valid_i*valid_j), so one
// sin/cos evaluates TWO directed elements — halves the trans-pipe work,
// which R2-R5 established as the issue-bound bottleneck (16 cyc/trans op).
// Block = one (it<=jt) 32x32 tile pair, 4 waves; lane = wavelength.
// I-side acc in registers (static idx), J-side acc via LDS float atomics.
// Both flushed to out with global atomicAdd (out pre-zeroed by memset).
__global__ __launch_bounds__(BLOCK) void spatial_embed_pairs(
    const float* __restrict__ x,            // [B, N, 3]
    const unsigned char* __restrict__ mask, // [B, N] bool (0 = valid)
    float* __restrict__ out,                // [B, N, DMODEL], pre-zeroed
    int B, int N)
{
    __shared__ float  xI[TILE][3], xJ[TILE][3];
    __shared__ float  validI[TILE], validJ[TILE];
    __shared__ float2 pairRV[TILE * TILE];    // {r, fused-valid 1/r}
    __shared__ float  jacc[TILE * DMODEL];    // J-side accumulator

    const int tid  = threadIdx.x;
    const int lane = tid & 63;
    const int wid  = tid >> 6;

    // decode (b, it, jt) from blockIdx (it <= jt)
    int tp = blockIdx.x % TPAIRS;
    const int b = blockIdx.x / TPAIRS;
    int it = 0;
    while (tp >= T_TILES - it) { tp -= T_TILES - it; ++it; }
    const int jt = it + tp;
    const bool diag = (it == jt);
    const int ibase = it * TILE, jbase = jt * TILE;

    // ---- phase 0: stage coords + masks; zero jacc ----
    if (tid < TILE) {
        const int g = b * N + ibase + tid;
        xI[tid][0] = x[g * 3 + 0]; xI[tid][1] = x[g * 3 + 1]; xI[tid][2] = x[g * 3 + 2];
        validI[tid] = (mask[g] == 0) ? 1.0f : 0.0f;
    } else if (tid < 2 * TILE) {
        const int r = tid - TILE;
        const int g = b * N + jbase + r;
        xJ[r][0] = x[g * 3 + 0]; xJ[r][1] = x[g * 3 + 1]; xJ[r][2] = x[g * 3 + 2];
        validJ[r] = (mask[g] == 0) ? 1.0f : 0.0f;
    }
    for (int k = tid; k < TILE * DMODEL; k += BLOCK) jacc[k] = 0.0f;
    __syncthreads();

    // ---- phase 1: r-tile with fused validity (ok/r = 0 when masked/self) ----
    for (int p = tid; p < TILE * TILE; p += BLOCK) {
        const int a = p >> 5, c = p & (TILE - 1);
        const float dx = xI[a][0] - xJ[c][0];
        const float dy = xI[a][1] - xJ[c][1];
        const float dz = xI[a][2] - xJ[c][2];
        const float r  = sqrtf(fmaf(dx, dx, fmaf(dy, dy, fmaf(dz, dz, 1e-6f))));
        float ok = validI[a] * validJ[c];
        if (diag && a >= c) ok = 0.0f;      // diag: keep a<c only (no self, no double-count)
        pairRV[p] = make_float2(r, ok / r);
    }
    __syncthreads();

    // ---- phase 2: wave wid owns I-rows wid*8..wid*8+7; lane = wavelength ----
    const float invlam = 0.5f * exp2f((float)lane * -0.07371200301229721f);

    float aR[8], aI[8];
    #pragma unroll
    for (int a = 0; a < 8; ++a) { aR[a] = 0.0f; aI[a] = 0.0f; }

    #pragma unroll
    for (int a = 0; a < 8; ++a) {
        const float2* rv = &pairRV[(wid * 8 + a) * TILE];
        for (int cc = 0; cc < TILE; ++cc) {
            const int c = (cc + wid * 8) & (TILE - 1);   // stagger waves across c
            const float2 p = rv[c];                      // ds_read_b64 broadcast
            const float rev = p.x * invlam;
            const float s  = __builtin_amdgcn_sinf(rev);
            const float co = __builtin_amdgcn_cosf(rev);
            aR[a] = fmaf(co, p.y, aR[a]);                // I-side (query = row a)
            aI[a] = fmaf(s,  p.y, aI[a]);
            atomicAdd(&jacc[c * DMODEL + 2 * lane],     co * p.y);  // J-side
            atomicAdd(&jacc[c * DMODEL + 2 * lane + 1], s  * p.y);
        }
    }

    // ---- phase 3a: I-side flush (rows distinct per wave) ----
    #pragma unroll
    for (int a = 0; a < 8; ++a) {
        const int grow = b * N + ibase + wid * 8 + a;
        atomicAdd(&out[grow * DMODEL + 2 * lane],     aR[a]);
        atomicAdd(&out[grow * DMODEL + 2 * lane + 1], aI[a]);
    }

    // ---- phase 3b: J-side flush from LDS ----
    __syncthreads();
    for (int k = tid; k < TILE * DMODEL; k += BLOCK) {
        const int c = k >> 7, col = k & (DMODEL - 1);
        atomicAdd(&out[(b * N + jbase + c) * DMODEL + col], jacc[k]);
    }
}

extern "C" void kernel_launch(void* const* d_in, const int* in_sizes, int n_in,
                              void* d_out, int out_size, void* d_ws, size_t ws_size,
                              hipStream_t stream) {
    const float* x = (const float*)d_in[0];
    const unsigned char* mask = (const unsigned char*)d_in[1];
    float* out = (float*)d_out;

    const int N = N_FIXED;
    const int BN = in_sizes[1];              // B*N
    const int B = BN / N;

    hipMemsetAsync(d_out, 0, (size_t)out_size * sizeof(float), stream);
    spatial_embed_pairs<<<dim3(B * TPAIRS), dim3(BLOCK), 0, stream>>>(x, mask, out, B, N);
}

// Round 7
// 48.695 us; speedup vs baseline: 10.4926x; 10.4926x over previous
//
#include <hip/hip_runtime.h>
#include <math.h>

#define NWAVE 64
#define DMODEL 128
#define BLOCK 256
#define N_FIXED 768
#define TILE 32
#define T_TILES (N_FIXED / TILE)              // 24
#define TPAIRS (T_TILES * (T_TILES + 1) / 2)  // 300

// Symmetric tile-pair kernel, REGISTER-ONLY inner loop (R6's LDS atomics in
// the hot loop were the 511us disaster). r_ij = r_ji and both directed
// contributions share the gate validI*validJ (query-side masking is applied
// by final zeroing, which atomics into a zeroed buffer preserve), so one
// sin/cos serves two output elements -> half the trans-pipe work, which is
// the measured bottleneck (1 trans wave-op per ~16 cyc per SIMD).
// Wave wid owns I-rows wid*8..+8 and accumulates: aR/aI[8] (I-side rows,
// static idx) and jR/jI[32] (J-side cols, static idx via full unroll).
// J-side: 4 sequential non-atomic LDS passes -> one atomic flush.
__global__ __launch_bounds__(BLOCK) void spatial_embed_pairs(
    const float* __restrict__ x,            // [B, N, 3]
    const unsigned char* __restrict__ mask, // [B, N] bool (0 = valid)
    float* __restrict__ out,                // [B, N, DMODEL], pre-zeroed
    int B, int N)
{
    __shared__ float xI[TILE][3], xJ[TILE][3];
    __shared__ float validI[TILE], validJ[TILE];
    __shared__ __align__(16) float2 pairRV[TILE * TILE];  // {r, ok/r}
    __shared__ float jaccR[TILE * 64];       // planar: [c][w]  (bank-friendly)
    __shared__ float jaccI[TILE * 64];

    const int tid  = threadIdx.x;
    const int lane = tid & 63;
    const int wid  = tid >> 6;

    // decode (b, it, jt), it <= jt
    int tp = blockIdx.x % TPAIRS;
    const int b = blockIdx.x / TPAIRS;
    int it = 0;
    while (tp >= T_TILES - it) { tp -= T_TILES - it; ++it; }
    const int jt = it + tp;
    const bool diag = (it == jt);
    const int ibase = it * TILE, jbase = jt * TILE;

    // ---- phase 0: stage coords + validity ----
    if (tid < TILE) {
        const int g = b * N + ibase + tid;
        xI[tid][0] = x[g * 3 + 0]; xI[tid][1] = x[g * 3 + 1]; xI[tid][2] = x[g * 3 + 2];
        validI[tid] = (mask[g] == 0) ? 1.0f : 0.0f;
    } else if (tid < 2 * TILE) {
        const int r = tid - TILE;
        const int g = b * N + jbase + r;
        xJ[r][0] = x[g * 3 + 0]; xJ[r][1] = x[g * 3 + 1]; xJ[r][2] = x[g * 3 + 2];
        validJ[r] = (mask[g] == 0) ? 1.0f : 0.0f;
    }
    __syncthreads();

    // ---- phase 1: r-tile + fused validity (4 distances/thread) ----
    for (int p = tid; p < TILE * TILE; p += BLOCK) {
        const int a = p >> 5, c = p & (TILE - 1);
        const float dx = xI[a][0] - xJ[c][0];
        const float dy = xI[a][1] - xJ[c][1];
        const float dz = xI[a][2] - xJ[c][2];
        const float d2 = fmaf(dx, dx, fmaf(dy, dy, fmaf(dz, dz, 1e-6f)));
        const float irs = __frsqrt_rn(d2);     // 1 trans instead of sqrt+rcp
        float ok = validI[a] * validJ[c];
        if (diag && a >= c) ok = 0.0f;          // diag: keep a<c only
        pairRV[p] = make_float2(d2 * irs, ok * irs);  // {r, ok/r}
    }
    __syncthreads();

    // ---- phase 2: register-only accumulation ----
    const float invlam = 0.5f * exp2f((float)lane * -0.07371200301229721f);

    float jR[TILE], jI[TILE];
    #pragma unroll
    for (int c = 0; c < TILE; ++c) { jR[c] = 0.0f; jI[c] = 0.0f; }

    const float4* rv4 = (const float4*)pairRV;  // {r0,v0,r1,v1} = 2 pairs

    #pragma unroll
    for (int a = 0; a < 8; ++a) {
        const int row = wid * 8 + a;
        float aR = 0.0f, aI = 0.0f;
        #pragma unroll
        for (int cp = 0; cp < TILE / 2; ++cp) {
            const float4 q = rv4[row * (TILE / 2) + cp];  // broadcast b128
            const float rev0 = q.x * invlam;
            const float s0 = __builtin_amdgcn_sinf(rev0);
            const float c0 = __builtin_amdgcn_cosf(rev0);
            aR = fmaf(c0, q.y, aR);              aI = fmaf(s0, q.y, aI);
            jR[2 * cp]     = fmaf(c0, q.y, jR[2 * cp]);
            jI[2 * cp]     = fmaf(s0, q.y, jI[2 * cp]);
            const float rev1 = q.z * invlam;
            const float s1 = __builtin_amdgcn_sinf(rev1);
            const float c1 = __builtin_amdgcn_cosf(rev1);
            aR = fmaf(c1, q.w, aR);              aI = fmaf(s1, q.w, aI);
            jR[2 * cp + 1] = fmaf(c1, q.w, jR[2 * cp + 1]);
            jI[2 * cp + 1] = fmaf(s1, q.w, jI[2 * cp + 1]);
        }
        // I-side flush: fire-and-forget atomics, overlap with next row's trans
        const int grow = b * N + ibase + row;
        atomicAdd(&out[grow * DMODEL + 2 * lane],     aR);
        atomicAdd(&out[grow * DMODEL + 2 * lane + 1], aI);
    }

    // ---- phase 3: J-side cross-wave reduce (sequential, NON-atomic LDS) ----
    for (int p = 0; p < 4; ++p) {
        if (wid == p) {
            if (p == 0) {
                #pragma unroll
                for (int c = 0; c < TILE; ++c) {
                    jaccR[c * 64 + lane] = jR[c];
                    jaccI[c * 64 + lane] = jI[c];
                }
            } else {
                #pragma unroll
                for (int c = 0; c < TILE; ++c) {
                    jaccR[c * 64 + lane] += jR[c];
                    jaccI[c * 64 + lane] += jI[c];
                }
            }
        }
        __syncthreads();
    }

    // ---- phase 4: J-side flush ----
    for (int k = tid; k < TILE * 64; k += BLOCK) {
        const int c = k >> 6, w = k & 63;
        const int grow = b * N + jbase + c;
        atomicAdd(&out[grow * DMODEL + 2 * w],     jaccR[k]);
        atomicAdd(&out[grow * DMODEL + 2 * w + 1], jaccI[k]);
    }
}

extern "C" void kernel_launch(void* const* d_in, const int* in_sizes, int n_in,
                              void* d_out, int out_size, void* d_ws, size_t ws_size,
                              hipStream_t stream) {
    const float* x = (const float*)d_in[0];
    const unsigned char* mask = (const unsigned char*)d_in[1];
    float* out = (float*)d_out;

    const int N = N_FIXED;
    const int BN = in_sizes[1];              // B*N
    const int B = BN / N;

    hipMemsetAsync(d_out, 0, (size_t)out_size * sizeof(float), stream);
    spatial_embed_pairs<<<dim3(B * TPAIRS), dim3(BLOCK), 0, stream>>>(x, mask, out, B, N);
}